// Round 10
// baseline (55.502 us; speedup 1.0000x reference)
//
#include <hip/hip_runtime.h>
#include <hip/hip_bf16.h>

// Problem constants (from reference): B=32, T=256, D=128, tau=0.02
#define B_SZ 32
#define T_SZ 256
#define D_SZ 128
#define TAU_INV 50.0f

typedef __bf16 bf16x8 __attribute__((ext_vector_type(8)));
typedef float f32x4 __attribute__((ext_vector_type(4)));

__device__ __forceinline__ unsigned short f2bf(float f) {
    union { float f; unsigned int u; } v; v.f = f;
    unsigned int r = v.u + 0x7fffu + ((v.u >> 16) & 1u);  // RNE
    return (unsigned short)(r >> 16);
}

// masks arrive either as int32 (harness "integer -> int*") or raw bool bytes.
// Element [0][0] is always true (q_len,p_len >= 64), so int32 layout reads 1,
// byte layout reads 0x01010101. Deterministic (input-only) detection.
__device__ __forceinline__ bool mask_is_byte(const void* m) {
    return ((const int*)m)[0] != 1;
}
__device__ __forceinline__ int mget(const void* m, int idx, bool isb) {
    return isb ? (((const unsigned char*)m)[idx] != 0) : (((const int*)m)[idx] != 0);
}

// ---------------- Kernel A: fp32->bf16 + mask tables ------------------------
// Blocks 0..1023: Q convert. 1024..2047: P convert. Block 2048: mask tables
// (maddF: 0/-1e30 per p token; qmulF: 1/0 per q token; p_hi per c; tcnt per b).
__global__ __launch_bounds__(256) void cvt_prep(
    const float* __restrict__ qsrc, const float* __restrict__ psrc,
    const void* __restrict__ qmask, const void* __restrict__ pmask,
    unsigned short* __restrict__ Qb, unsigned short* __restrict__ Pb,
    float* __restrict__ maddF, float* __restrict__ qmulF,
    int* __restrict__ p_hiA, float* __restrict__ tcntA) {
    const int tid = threadIdx.x;
    const int half = blockIdx.x >> 10;           // 0:Q 1:P 2:tables
    if (half < 2) {
        const float* s = half ? psrc : qsrc;
        unsigned short* d = half ? Pb : Qb;
        int i = ((blockIdx.x & 1023) * 256 + tid) * 4;
        float4 v = *(const float4*)(s + i);
        ushort4 o;
        o.x = f2bf(v.x); o.y = f2bf(v.y); o.z = f2bf(v.z); o.w = f2bf(v.w);
        *(ushort4*)(d + i) = o;
        return;
    }
    // ---- tables ----
    const bool isb = mask_is_byte(qmask);
    for (int idx = tid; idx < B_SZ * T_SZ; idx += 256) {
        maddF[idx] = mget(pmask, idx, isb) ? 0.0f : -1e30f;
        qmulF[idx] = mget(qmask, idx, isb) ? 1.0f : 0.0f;
    }
    // p_hi per c and tcnt per b: 8 threads/row, 32 tokens each, shuffle-combine
    const int r = tid >> 3, j = tid & 7;
    int last_p = 0, cntq = 0;
    for (int t = j * 32; t < j * 32 + 32; ++t) {
        if (mget(pmask, r * T_SZ + t, isb)) last_p = t + 1;
        cntq += mget(qmask, r * T_SZ + t, isb);
    }
    #pragma unroll
    for (int off = 1; off < 8; off <<= 1) {
        int lp = __shfl_xor(last_p, off);
        last_p = lp > last_p ? lp : last_p;
        cntq += __shfl_xor(cntq, off);
    }
    if (j == 0) {
        p_hiA[r] = last_p > 1 ? last_p : 1;
        tcntA[r] = (float)(cntq > 1 ? cntq : 1);
    }
}

// ---------------- Kernel B: late-interaction scores -------------------------
// XCD-aware mapping: XCD x (bid&7) hosts bg in {2x,2x+1} x all 32 c ->
// per-XCD working set (4 Q slices + 32 P tiles, bf16) ~2.25 MB, L2-resident.
// P staged via global_load_lds (16B, linear LDS dest + inverse-swizzled
// global source); MFMA reads apply the XOR swizzle -> net identity, no bank
// pileup. Masked work-skip is exact (p tiles past p_hi never win the max,
// masked q rows multiply by 0).
__global__ __launch_bounds__(512, 4) void late_sim(
    const unsigned short* __restrict__ Qbf, const unsigned short* __restrict__ Pbf,
    const float* __restrict__ maddF, const float* __restrict__ qmulF,
    const int* __restrict__ p_hiA, float* __restrict__ sraw)
{
    __shared__ __align__(16) unsigned char Plds[T_SZ * D_SZ * 2]; // 64 KB
    __shared__ float madd[T_SZ];
    __shared__ float qmul[2][T_SZ];
    __shared__ float wsum[2][8];

    const int tid = threadIdx.x;
    const int l   = tid & 63;
    const int w   = tid >> 6;        // wave 0..7
    const int bid = blockIdx.x;
    const int xcd = bid & 7;
    const int idx = bid >> 3;        // 0..63
    const int bg  = xcd * 2 + (idx >> 5);  // XCD-local bg pair
    const int c   = idx & 31;
    const int b0  = bg, b1 = bg + 16;
    const int lr  = l & 15;
    const int lg  = l >> 4;

    const int p_hi    = p_hiA[c];
    const int ptmax   = (p_hi + 15) >> 4;   // 16-row MFMA tiles
    const int stiters = (p_hi + 31) >> 5;   // 32-row staging iterations

    // wave-uniform q-tile activity
    const int qrow = w * 32 + (l & 31);
    const bool do0 = __any(qmulF[b0 * T_SZ + qrow] > 0.0f);
    const bool do1 = __any(qmulF[b1 * T_SZ + qrow] > 0.0f);

    // Q fragments FIRST (in flight while staging runs):
    // lane holds Q[w*32+qt*16+lr][k*32+lg*8 .. +7]
    bf16x8 qf0[2][4] = {}, qf1[2][4] = {};
    if (do0)
        #pragma unroll
        for (int qt = 0; qt < 2; ++qt)
            #pragma unroll
            for (int k = 0; k < 4; ++k)
                qf0[qt][k] = *(const bf16x8*)(Qbf + b0 * (T_SZ * D_SZ)
                              + (w * 32 + qt * 16 + lr) * D_SZ + k * 32 + lg * 8);
    if (do1)
        #pragma unroll
        for (int qt = 0; qt < 2; ++qt)
            #pragma unroll
            for (int k = 0; k < 4; ++k)
                qf1[qt][k] = *(const bf16x8*)(Qbf + b1 * (T_SZ * D_SZ)
                              + (w * 32 + qt * 16 + lr) * D_SZ + k * 32 + lg * 8);

    // stage P rows [0, stiters*32): global_load_lds, linear LDS dest,
    // inverse-swizzled global source (read-side XOR makes it net-identity)
    {
        const unsigned short* Pc = Pbf + c * (T_SZ * D_SZ);
        for (int it = 0; it < stiters; ++it) {
            int j   = it * 512 + w * 64 + l;     // linear 16B chunk id
            int row = j >> 4;
            int cj  = j & 15;
            const unsigned short* src = Pc + row * D_SZ + ((cj ^ (row & 7)) << 3);
            __builtin_amdgcn_global_load_lds(
                (const __attribute__((address_space(1))) unsigned int*)src,
                (__attribute__((address_space(3))) unsigned int*)(Plds + (it * 512 + w * 64) * 16),
                16, 0, 0);
        }
    }
    // mask vectors LDS fill (vectorized from precomputed tables)
    if (tid < 64) {
        *(float4*)(madd + tid * 4) = *(const float4*)(maddF + c * T_SZ + tid * 4);
    } else if (tid < 128) {
        int t = tid - 64;
        *(float4*)(qmul[0] + t * 4) = *(const float4*)(qmulF + b0 * T_SZ + t * 4);
    } else if (tid < 192) {
        int t = tid - 128;
        *(float4*)(qmul[1] + t * 4) = *(const float4*)(qmulF + b1 * T_SZ + t * 4);
    }
    __syncthreads();   // drains vmcnt(0): staging + qf loads complete

    float r00 = -3e38f, r01 = -3e38f, r10 = -3e38f, r11 = -3e38f;

    for (int pt = 0; pt < ptmax; ++pt) {
        f32x4 a00 = {0,0,0,0}, a01 = {0,0,0,0}, a10 = {0,0,0,0}, a11 = {0,0,0,0};
        #pragma unroll
        for (int k = 0; k < 4; ++k) {
            int row = pt * 16 + lr;
            bf16x8 af = *(const bf16x8*)(Plds + row * 256 + (((k * 4 + lg) ^ (row & 7)) << 4));
            if (do0) {
                a00 = __builtin_amdgcn_mfma_f32_16x16x32_bf16(af, qf0[0][k], a00, 0, 0, 0);
                a01 = __builtin_amdgcn_mfma_f32_16x16x32_bf16(af, qf0[1][k], a01, 0, 0, 0);
            }
            if (do1) {
                a10 = __builtin_amdgcn_mfma_f32_16x16x32_bf16(af, qf1[0][k], a10, 0, 0, 0);
                a11 = __builtin_amdgcn_mfma_f32_16x16x32_bf16(af, qf1[1][k], a11, 0, 0, 0);
            }
        }
        // C layout: col(q)=lane&15, row(p)= pt*16 + lg*4 + reg
        float pm0 = madd[pt * 16 + lg * 4 + 0];
        float pm1 = madd[pt * 16 + lg * 4 + 1];
        float pm2 = madd[pt * 16 + lg * 4 + 2];
        float pm3v = madd[pt * 16 + lg * 4 + 3];
        if (do0) {
            r00 = fmaxf(r00, fmaxf(fmaxf(a00[0]+pm0, a00[1]+pm1), fmaxf(a00[2]+pm2, a00[3]+pm3v)));
            r01 = fmaxf(r01, fmaxf(fmaxf(a01[0]+pm0, a01[1]+pm1), fmaxf(a01[2]+pm2, a01[3]+pm3v)));
        }
        if (do1) {
            r10 = fmaxf(r10, fmaxf(fmaxf(a10[0]+pm0, a10[1]+pm1), fmaxf(a10[2]+pm2, a10[3]+pm3v)));
            r11 = fmaxf(r11, fmaxf(fmaxf(a11[0]+pm0, a11[1]+pm1), fmaxf(a11[2]+pm2, a11[3]+pm3v)));
        }
    }

    // combine the 4 row-groups (lanes x, 16+x, 32+x, 48+x)
    r00 = fmaxf(r00, __shfl_xor(r00, 16)); r00 = fmaxf(r00, __shfl_xor(r00, 32));
    r01 = fmaxf(r01, __shfl_xor(r01, 16)); r01 = fmaxf(r01, __shfl_xor(r01, 32));
    r10 = fmaxf(r10, __shfl_xor(r10, 16)); r10 = fmaxf(r10, __shfl_xor(r10, 32));
    r11 = fmaxf(r11, __shfl_xor(r11, 16)); r11 = fmaxf(r11, __shfl_xor(r11, 32));

    // masked sum over this wave's 32 q tokens (each value replicated 4x)
    float t0 = r00 * qmul[0][w * 32 + lr] + r01 * qmul[0][w * 32 + 16 + lr];
    float t1 = r10 * qmul[1][w * 32 + lr] + r11 * qmul[1][w * 32 + 16 + lr];
    #pragma unroll
    for (int off = 32; off > 0; off >>= 1) {
        t0 += __shfl_down(t0, off);
        t1 += __shfl_down(t1, off);
    }
    if (l == 0) { wsum[0][w] = t0 * 0.25f; wsum[1][w] = t1 * 0.25f; }
    __syncthreads();

    if (tid == 0) {
        float s0 = 0.f, s1 = 0.f;
        #pragma unroll
        for (int ww = 0; ww < 8; ++ww) { s0 += wsum[0][ww]; s1 += wsum[1][ww]; }
        sraw[b0 * 32 + c] = s0;
        sraw[b1 * 32 + c] = s1;
    }
}

// ---------------- Kernel C: dense sim + losses (1 block, parallel) ----------
__global__ __launch_bounds__(256) void loss_final(
    const float* __restrict__ qs, const float* __restrict__ ps,
    const float* __restrict__ sraw, const float* __restrict__ tcntA,
    float* __restrict__ out)
{
    __shared__ float qsL[B_SZ * 132];
    __shared__ float psL[B_SZ * 132];
    __shared__ float dense[B_SZ * B_SZ];
    __shared__ float late[B_SZ * B_SZ];
    __shared__ float tcnt[B_SZ];
    __shared__ float rsA[B_SZ], rmA[B_SZ], rkA[B_SZ];

    const int tid = threadIdx.x;

    for (int i = tid; i < 1024; i += 256) {     // 1024 float4 slots per array
        int r = i >> 5, c4 = (i & 31) * 4;
        *(float4*)(qsL + r * 132 + c4) = *(const float4*)(qs + r * D_SZ + c4);
        *(float4*)(psL + r * 132 + c4) = *(const float4*)(ps + r * D_SZ + c4);
    }
    if (tid < B_SZ) tcnt[tid] = tcntA[tid];     // precomputed in cvt_prep
    __syncthreads();

    for (int idx = tid; idx < B_SZ * B_SZ; idx += 256) {  // 4 (r,c) pairs/thread
        int r = idx >> 5, cc = idx & 31;
        float s = 0.f;
        #pragma unroll
        for (int i = 0; i < D_SZ; i += 4) {
            float4 a  = *(const float4*)(qsL + r  * 132 + i);
            float4 bb = *(const float4*)(psL + cc * 132 + i);
            s += a.x * bb.x + a.y * bb.y + a.z * bb.z + a.w * bb.w;
        }
        dense[r * 32 + cc] = s;
        late[r * 32 + cc]  = sraw[idx] / tcnt[r];
    }
    __syncthreads();

    // per-row softmax/CE/KL: 8 rows per pass, 32 lanes per row
    {
        const int cc = tid & 31;
        #pragma unroll
        for (int it = 0; it < 4; ++it) {
            const int r = (tid >> 5) + 8 * it;
            float xd = dense[r * 32 + cc] * TAU_INV;
            float xl = late[r * 32 + cc]  * TAU_INV;
            float md = xd, ml = xl;
            #pragma unroll
            for (int off = 16; off > 0; off >>= 1) {
                md = fmaxf(md, __shfl_xor(md, off));
                ml = fmaxf(ml, __shfl_xor(ml, off));
            }
            float sd = expf(xd - md), sl = expf(xl - ml);
            #pragma unroll
            for (int off = 16; off > 0; off >>= 1) {
                sd += __shfl_xor(sd, off);
                sl += __shfl_xor(sl, off);
            }
            float lsd = md + logf(sd);
            float lsl = ml + logf(sl);
            float pd = expf(xd - lsd);
            float pl = expf(xl - lsl);
            float klt = pd * logf((pd + 1e-8f) / (pl + 1e-8f));
            #pragma unroll
            for (int off = 16; off > 0; off >>= 1) klt += __shfl_xor(klt, off);
            if (cc == 0) rkA[r] = klt;
            if (cc == r) { rsA[r] = -(xd - lsd); rmA[r] = -(xl - lsl); }
        }
    }
    __syncthreads();

    if (tid < B_SZ) {
        float a = rsA[tid], bb = rmA[tid], c2 = rkA[tid];
        #pragma unroll
        for (int off = 16; off > 0; off >>= 1) {
            a  += __shfl_xor(a, off);
            bb += __shfl_xor(bb, off);
            c2 += __shfl_xor(c2, off);
        }
        if (tid == 0) {
            a *= (1.0f / B_SZ); bb *= (1.0f / B_SZ); c2 *= (1.0f / B_SZ);
            out[0] = a + bb + c2;  // total
            out[1] = a;            // single_loss
            out[2] = bb;           // multi_loss
            out[3] = c2;           // kl
        }
    }
}

// ---------------------------------------------------------------------------
extern "C" void kernel_launch(void* const* d_in, const int* in_sizes, int n_in,
                              void* d_out, int out_size, void* d_ws, size_t ws_size,
                              hipStream_t stream) {
    const float* qs    = (const float*)d_in[0];  // query_single [32,128]
    const float* ps    = (const float*)d_in[1];  // pos_single   [32,128]
    const float* qm3   = (const float*)d_in[2];  // query_multi  [32,256,128]
    const float* pm3   = (const float*)d_in[3];  // pos_multi    [32,256,128]
    const void*  qmask = d_in[4];                // q_mask [32,256]
    const void*  pmask = d_in[5];                // p_mask [32,256]
    float* out = (float*)d_out;

    const int NTOK = B_SZ * T_SZ * D_SZ;         // 1,048,576
    unsigned short* Qbf = (unsigned short*)d_ws;
    unsigned short* Pbf = Qbf + NTOK;
    float* sraw  = (float*)(Pbf + NTOK);         // [1024]
    float* maddF = sraw + 1024;                  // [32*256]
    float* qmulF = maddF + B_SZ * T_SZ;          // [32*256]
    int*   p_hiA = (int*)(qmulF + B_SZ * T_SZ);  // [32]
    float* tcntA = (float*)(p_hiA + 32);         // [32]

    cvt_prep<<<2049, 256, 0, stream>>>(qm3, pm3, qmask, pmask, Qbf, Pbf,
                                       maddF, qmulF, p_hiA, tcntA);
    late_sim<<<512, 512, 0, stream>>>(Qbf, Pbf, maddF, qmulF, p_hiA, sraw);
    loss_final<<<1, 256, 0, stream>>>(qs, ps, sraw, tcntA, out);
}

// Round 11
// 38.127 us; speedup vs baseline: 1.4557x; 1.4557x over previous
//
#include <hip/hip_runtime.h>
#include <hip/hip_bf16.h>

// Problem constants (from reference): B=32, T=256, D=128, tau=0.02
#define B_SZ 32
#define T_SZ 256
#define D_SZ 128
#define TAU_INV 50.0f

typedef __bf16 bf16x8 __attribute__((ext_vector_type(8)));
typedef float f32x4 __attribute__((ext_vector_type(4)));

__device__ __forceinline__ unsigned short f2bf(float f) {
    union { float f; unsigned int u; } v; v.f = f;
    unsigned int r = v.u + 0x7fffu + ((v.u >> 16) & 1u);  // RNE
    return (unsigned short)(r >> 16);
}

// masks arrive either as int32 (harness "integer -> int*") or raw bool bytes.
// Element [0][0] is always true (q_len,p_len >= 64), so int32 layout reads 1,
// byte layout reads 0x01010101. Deterministic (input-only) detection.
__device__ __forceinline__ bool mask_is_byte(const void* m) {
    return ((const int*)m)[0] != 1;
}
__device__ __forceinline__ int mget(const void* m, int idx, bool isb) {
    return isb ? (((const unsigned char*)m)[idx] != 0) : (((const int*)m)[idx] != 0);
}

// ---------------- Kernel A: fp32->bf16 + mask tables (parallel) -------------
// Blocks 0..1023: Q convert. 1024..2047: P convert. Blocks 2048..2079: one
// block per batch row r -> maddF/qmulF (1 thread/token), p_hi[r], tcnt[r].
__global__ __launch_bounds__(256) void cvt_prep(
    const float* __restrict__ qsrc, const float* __restrict__ psrc,
    const void* __restrict__ qmask, const void* __restrict__ pmask,
    unsigned short* __restrict__ Qb, unsigned short* __restrict__ Pb,
    float* __restrict__ maddF, float* __restrict__ qmulF,
    int* __restrict__ p_hiA, float* __restrict__ tcntA) {
    const int tid = threadIdx.x;
    const int half = blockIdx.x >> 10;           // 0:Q 1:P 2:tables
    if (half < 2) {
        const float* s = half ? psrc : qsrc;
        unsigned short* d = half ? Pb : Qb;
        int i = ((blockIdx.x & 1023) * 256 + tid) * 4;
        float4 v = *(const float4*)(s + i);
        ushort4 o;
        o.x = f2bf(v.x); o.y = f2bf(v.y); o.z = f2bf(v.z); o.w = f2bf(v.w);
        *(ushort4*)(d + i) = o;
        return;
    }
    // ---- table row r: 1 thread per token, wave+LDS reduce ----
    __shared__ int sl[4], sc[4];
    const bool isb = mask_is_byte(qmask);
    const int r = blockIdx.x - 2048;             // 0..31
    const int t = tid;                           // 0..255 (= T_SZ)
    const int pm = mget(pmask, r * T_SZ + t, isb);
    const int qm = mget(qmask, r * T_SZ + t, isb);
    maddF[r * T_SZ + t] = pm ? 0.0f : -1e30f;
    qmulF[r * T_SZ + t] = qm ? 1.0f : 0.0f;
    int lp = pm ? t + 1 : 0, cq = qm;
    #pragma unroll
    for (int off = 1; off < 64; off <<= 1) {
        int o = __shfl_xor(lp, off);
        lp = o > lp ? o : lp;
        cq += __shfl_xor(cq, off);
    }
    if ((tid & 63) == 0) { sl[tid >> 6] = lp; sc[tid >> 6] = cq; }
    __syncthreads();
    if (tid == 0) {
        int LP = sl[0], CQ = sc[0];
        #pragma unroll
        for (int i = 1; i < 4; ++i) { LP = sl[i] > LP ? sl[i] : LP; CQ += sc[i]; }
        p_hiA[r] = LP > 1 ? LP : 1;
        tcntA[r] = (float)(CQ > 1 ? CQ : 1);
    }
}

// ---------------- Kernel B: late-interaction scores -------------------------
// XCD-aware mapping: XCD x (bid&7) hosts bg in {2x,2x+1} x all 32 c ->
// per-XCD working set (4 Q slices + 32 P tiles, bf16) ~2.25 MB, L2-resident.
// P staged via global_load_lds (16B, linear LDS dest + inverse-swizzled
// global source); MFMA reads apply the XOR swizzle -> net identity, no bank
// pileup. Masked work-skip is exact (p tiles past p_hi never win the max,
// masked q rows multiply by 0).
__global__ __launch_bounds__(512, 4) void late_sim(
    const unsigned short* __restrict__ Qbf, const unsigned short* __restrict__ Pbf,
    const float* __restrict__ maddF, const float* __restrict__ qmulF,
    const int* __restrict__ p_hiA, float* __restrict__ sraw)
{
    __shared__ __align__(16) unsigned char Plds[T_SZ * D_SZ * 2]; // 64 KB
    __shared__ float madd[T_SZ];
    __shared__ float qmul[2][T_SZ];
    __shared__ float wsum[2][8];

    const int tid = threadIdx.x;
    const int l   = tid & 63;
    const int w   = tid >> 6;        // wave 0..7
    const int bid = blockIdx.x;
    const int xcd = bid & 7;
    const int idx = bid >> 3;        // 0..63
    const int bg  = xcd * 2 + (idx >> 5);  // XCD-local bg pair
    const int c   = idx & 31;
    const int b0  = bg, b1 = bg + 16;
    const int lr  = l & 15;
    const int lg  = l >> 4;

    const int p_hi    = p_hiA[c];
    const int ptmax   = (p_hi + 15) >> 4;   // 16-row MFMA tiles
    const int stiters = (p_hi + 31) >> 5;   // 32-row staging iterations

    // wave-uniform q-tile activity
    const int qrow = w * 32 + (l & 31);
    const bool do0 = __any(qmulF[b0 * T_SZ + qrow] > 0.0f);
    const bool do1 = __any(qmulF[b1 * T_SZ + qrow] > 0.0f);

    // Q fragments FIRST (in flight while staging runs):
    // lane holds Q[w*32+qt*16+lr][k*32+lg*8 .. +7]
    bf16x8 qf0[2][4] = {}, qf1[2][4] = {};
    if (do0)
        #pragma unroll
        for (int qt = 0; qt < 2; ++qt)
            #pragma unroll
            for (int k = 0; k < 4; ++k)
                qf0[qt][k] = *(const bf16x8*)(Qbf + b0 * (T_SZ * D_SZ)
                              + (w * 32 + qt * 16 + lr) * D_SZ + k * 32 + lg * 8);
    if (do1)
        #pragma unroll
        for (int qt = 0; qt < 2; ++qt)
            #pragma unroll
            for (int k = 0; k < 4; ++k)
                qf1[qt][k] = *(const bf16x8*)(Qbf + b1 * (T_SZ * D_SZ)
                              + (w * 32 + qt * 16 + lr) * D_SZ + k * 32 + lg * 8);

    // stage P rows [0, stiters*32): global_load_lds, linear LDS dest,
    // inverse-swizzled global source (read-side XOR makes it net-identity)
    {
        const unsigned short* Pc = Pbf + c * (T_SZ * D_SZ);
        for (int it = 0; it < stiters; ++it) {
            int j   = it * 512 + w * 64 + l;     // linear 16B chunk id
            int row = j >> 4;
            int cj  = j & 15;
            const unsigned short* src = Pc + row * D_SZ + ((cj ^ (row & 7)) << 3);
            __builtin_amdgcn_global_load_lds(
                (const __attribute__((address_space(1))) unsigned int*)src,
                (__attribute__((address_space(3))) unsigned int*)(Plds + (it * 512 + w * 64) * 16),
                16, 0, 0);
        }
    }
    // mask vectors LDS fill (vectorized from precomputed tables)
    if (tid < 64) {
        *(float4*)(madd + tid * 4) = *(const float4*)(maddF + c * T_SZ + tid * 4);
    } else if (tid < 128) {
        int t = tid - 64;
        *(float4*)(qmul[0] + t * 4) = *(const float4*)(qmulF + b0 * T_SZ + t * 4);
    } else if (tid < 192) {
        int t = tid - 128;
        *(float4*)(qmul[1] + t * 4) = *(const float4*)(qmulF + b1 * T_SZ + t * 4);
    }
    __syncthreads();   // drains vmcnt(0): staging + qf loads complete

    float r00 = -3e38f, r01 = -3e38f, r10 = -3e38f, r11 = -3e38f;

    for (int pt = 0; pt < ptmax; ++pt) {
        f32x4 a00 = {0,0,0,0}, a01 = {0,0,0,0}, a10 = {0,0,0,0}, a11 = {0,0,0,0};
        #pragma unroll
        for (int k = 0; k < 4; ++k) {
            int row = pt * 16 + lr;
            bf16x8 af = *(const bf16x8*)(Plds + row * 256 + (((k * 4 + lg) ^ (row & 7)) << 4));
            if (do0) {
                a00 = __builtin_amdgcn_mfma_f32_16x16x32_bf16(af, qf0[0][k], a00, 0, 0, 0);
                a01 = __builtin_amdgcn_mfma_f32_16x16x32_bf16(af, qf0[1][k], a01, 0, 0, 0);
            }
            if (do1) {
                a10 = __builtin_amdgcn_mfma_f32_16x16x32_bf16(af, qf1[0][k], a10, 0, 0, 0);
                a11 = __builtin_amdgcn_mfma_f32_16x16x32_bf16(af, qf1[1][k], a11, 0, 0, 0);
            }
        }
        // C layout: col(q)=lane&15, row(p)= pt*16 + lg*4 + reg
        float pm0 = madd[pt * 16 + lg * 4 + 0];
        float pm1 = madd[pt * 16 + lg * 4 + 1];
        float pm2 = madd[pt * 16 + lg * 4 + 2];
        float pm3v = madd[pt * 16 + lg * 4 + 3];
        if (do0) {
            r00 = fmaxf(r00, fmaxf(fmaxf(a00[0]+pm0, a00[1]+pm1), fmaxf(a00[2]+pm2, a00[3]+pm3v)));
            r01 = fmaxf(r01, fmaxf(fmaxf(a01[0]+pm0, a01[1]+pm1), fmaxf(a01[2]+pm2, a01[3]+pm3v)));
        }
        if (do1) {
            r10 = fmaxf(r10, fmaxf(fmaxf(a10[0]+pm0, a10[1]+pm1), fmaxf(a10[2]+pm2, a10[3]+pm3v)));
            r11 = fmaxf(r11, fmaxf(fmaxf(a11[0]+pm0, a11[1]+pm1), fmaxf(a11[2]+pm2, a11[3]+pm3v)));
        }
    }

    // combine the 4 row-groups (lanes x, 16+x, 32+x, 48+x)
    r00 = fmaxf(r00, __shfl_xor(r00, 16)); r00 = fmaxf(r00, __shfl_xor(r00, 32));
    r01 = fmaxf(r01, __shfl_xor(r01, 16)); r01 = fmaxf(r01, __shfl_xor(r01, 32));
    r10 = fmaxf(r10, __shfl_xor(r10, 16)); r10 = fmaxf(r10, __shfl_xor(r10, 32));
    r11 = fmaxf(r11, __shfl_xor(r11, 16)); r11 = fmaxf(r11, __shfl_xor(r11, 32));

    // masked sum over this wave's 32 q tokens (each value replicated 4x)
    float t0 = r00 * qmul[0][w * 32 + lr] + r01 * qmul[0][w * 32 + 16 + lr];
    float t1 = r10 * qmul[1][w * 32 + lr] + r11 * qmul[1][w * 32 + 16 + lr];
    #pragma unroll
    for (int off = 32; off > 0; off >>= 1) {
        t0 += __shfl_down(t0, off);
        t1 += __shfl_down(t1, off);
    }
    if (l == 0) { wsum[0][w] = t0 * 0.25f; wsum[1][w] = t1 * 0.25f; }
    __syncthreads();

    if (tid == 0) {
        float s0 = 0.f, s1 = 0.f;
        #pragma unroll
        for (int ww = 0; ww < 8; ++ww) { s0 += wsum[0][ww]; s1 += wsum[1][ww]; }
        sraw[b0 * 32 + c] = s0;
        sraw[b1 * 32 + c] = s1;
    }
}

// ---------------- Kernel C: dense sim + losses (1 block, parallel) ----------
__global__ __launch_bounds__(256) void loss_final(
    const float* __restrict__ qs, const float* __restrict__ ps,
    const float* __restrict__ sraw, const float* __restrict__ tcntA,
    float* __restrict__ out)
{
    __shared__ float qsL[B_SZ * 132];
    __shared__ float psL[B_SZ * 132];
    __shared__ float dense[B_SZ * B_SZ];
    __shared__ float late[B_SZ * B_SZ];
    __shared__ float tcnt[B_SZ];
    __shared__ float rsA[B_SZ], rmA[B_SZ], rkA[B_SZ];

    const int tid = threadIdx.x;

    for (int i = tid; i < 1024; i += 256) {     // 1024 float4 slots per array
        int r = i >> 5, c4 = (i & 31) * 4;
        *(float4*)(qsL + r * 132 + c4) = *(const float4*)(qs + r * D_SZ + c4);
        *(float4*)(psL + r * 132 + c4) = *(const float4*)(ps + r * D_SZ + c4);
    }
    if (tid < B_SZ) tcnt[tid] = tcntA[tid];     // precomputed in cvt_prep
    __syncthreads();

    for (int idx = tid; idx < B_SZ * B_SZ; idx += 256) {  // 4 (r,c) pairs/thread
        int r = idx >> 5, cc = idx & 31;
        float s = 0.f;
        #pragma unroll
        for (int i = 0; i < D_SZ; i += 4) {
            float4 a  = *(const float4*)(qsL + r  * 132 + i);
            float4 bb = *(const float4*)(psL + cc * 132 + i);
            s += a.x * bb.x + a.y * bb.y + a.z * bb.z + a.w * bb.w;
        }
        dense[r * 32 + cc] = s;
        late[r * 32 + cc]  = sraw[idx] / tcnt[r];
    }
    __syncthreads();

    // per-row softmax/CE/KL: 8 rows per pass, 32 lanes per row
    {
        const int cc = tid & 31;
        #pragma unroll
        for (int it = 0; it < 4; ++it) {
            const int r = (tid >> 5) + 8 * it;
            float xd = dense[r * 32 + cc] * TAU_INV;
            float xl = late[r * 32 + cc]  * TAU_INV;
            float md = xd, ml = xl;
            #pragma unroll
            for (int off = 16; off > 0; off >>= 1) {
                md = fmaxf(md, __shfl_xor(md, off));
                ml = fmaxf(ml, __shfl_xor(ml, off));
            }
            float sd = expf(xd - md), sl = expf(xl - ml);
            #pragma unroll
            for (int off = 16; off > 0; off >>= 1) {
                sd += __shfl_xor(sd, off);
                sl += __shfl_xor(sl, off);
            }
            float lsd = md + logf(sd);
            float lsl = ml + logf(sl);
            float pd = expf(xd - lsd);
            float pl = expf(xl - lsl);
            float klt = pd * logf((pd + 1e-8f) / (pl + 1e-8f));
            #pragma unroll
            for (int off = 16; off > 0; off >>= 1) klt += __shfl_xor(klt, off);
            if (cc == 0) rkA[r] = klt;
            if (cc == r) { rsA[r] = -(xd - lsd); rmA[r] = -(xl - lsl); }
        }
    }
    __syncthreads();

    if (tid < B_SZ) {
        float a = rsA[tid], bb = rmA[tid], c2 = rkA[tid];
        #pragma unroll
        for (int off = 16; off > 0; off >>= 1) {
            a  += __shfl_xor(a, off);
            bb += __shfl_xor(bb, off);
            c2 += __shfl_xor(c2, off);
        }
        if (tid == 0) {
            a *= (1.0f / B_SZ); bb *= (1.0f / B_SZ); c2 *= (1.0f / B_SZ);
            out[0] = a + bb + c2;  // total
            out[1] = a;            // single_loss
            out[2] = bb;           // multi_loss
            out[3] = c2;           // kl
        }
    }
}

// ---------------------------------------------------------------------------
extern "C" void kernel_launch(void* const* d_in, const int* in_sizes, int n_in,
                              void* d_out, int out_size, void* d_ws, size_t ws_size,
                              hipStream_t stream) {
    const float* qs    = (const float*)d_in[0];  // query_single [32,128]
    const float* ps    = (const float*)d_in[1];  // pos_single   [32,128]
    const float* qm3   = (const float*)d_in[2];  // query_multi  [32,256,128]
    const float* pm3   = (const float*)d_in[3];  // pos_multi    [32,256,128]
    const void*  qmask = d_in[4];                // q_mask [32,256]
    const void*  pmask = d_in[5];                // p_mask [32,256]
    float* out = (float*)d_out;

    const int NTOK = B_SZ * T_SZ * D_SZ;         // 1,048,576
    unsigned short* Qbf = (unsigned short*)d_ws;
    unsigned short* Pbf = Qbf + NTOK;
    float* sraw  = (float*)(Pbf + NTOK);         // [1024]
    float* maddF = sraw + 1024;                  // [32*256]
    float* qmulF = maddF + B_SZ * T_SZ;          // [32*256]
    int*   p_hiA = (int*)(qmulF + B_SZ * T_SZ);  // [32]
    float* tcntA = (float*)(p_hiA + 32);         // [32]

    cvt_prep<<<2080, 256, 0, stream>>>(qm3, pm3, qmask, pmask, Qbf, Pbf,
                                       maddF, qmulF, p_hiA, tcntA);
    late_sim<<<512, 512, 0, stream>>>(Qbf, Pbf, maddF, qmulF, p_hiA, sraw);
    loss_final<<<1, 256, 0, stream>>>(qs, ps, sraw, tcntA, out);
}

// Round 13
// 35.734 us; speedup vs baseline: 1.5532x; 1.0670x over previous
//
#include <hip/hip_runtime.h>
#include <hip/hip_bf16.h>

// Problem constants (from reference): B=32, T=256, D=128, tau=0.02
#define B_SZ 32
#define T_SZ 256
#define D_SZ 128
#define TAU_INV 50.0f

typedef __bf16 bf16x8 __attribute__((ext_vector_type(8)));
typedef float f32x4 __attribute__((ext_vector_type(4)));

__device__ __forceinline__ unsigned short f2bf(float f) {
    union { float f; unsigned int u; } v; v.f = f;
    unsigned int r = v.u + 0x7fffu + ((v.u >> 16) & 1u);  // RNE
    return (unsigned short)(r >> 16);
}

// masks arrive either as int32 (harness "integer -> int*") or raw bool bytes.
// Element [0][0] is always true (q_len,p_len >= 64), so int32 layout reads 1,
// byte layout reads 0x01010101. Deterministic (input-only) detection.
__device__ __forceinline__ bool mask_is_byte(const void* m) {
    return ((const int*)m)[0] != 1;
}
__device__ __forceinline__ int mget(const void* m, int idx, bool isb) {
    return isb ? (((const unsigned char*)m)[idx] != 0) : (((const int*)m)[idx] != 0);
}

// ---------------- Kernel A: fp32->bf16 + mask tables (parallel) -------------
// Blocks 0..1023: Q convert. 1024..2047: P convert. Blocks 2048..2079: one
// block per batch row r -> maddF/qmulF (1 thread/token), p_hi[r], tcnt[r].
__global__ __launch_bounds__(256) void cvt_prep(
    const float* __restrict__ qsrc, const float* __restrict__ psrc,
    const void* __restrict__ qmask, const void* __restrict__ pmask,
    unsigned short* __restrict__ Qb, unsigned short* __restrict__ Pb,
    float* __restrict__ maddF, float* __restrict__ qmulF,
    int* __restrict__ p_hiA, float* __restrict__ tcntA) {
    const int tid = threadIdx.x;
    const int half = blockIdx.x >> 10;           // 0:Q 1:P 2:tables
    if (half < 2) {
        const float* s = half ? psrc : qsrc;
        unsigned short* d = half ? Pb : Qb;
        int i = ((blockIdx.x & 1023) * 256 + tid) * 4;
        float4 v = *(const float4*)(s + i);
        ushort4 o;
        o.x = f2bf(v.x); o.y = f2bf(v.y); o.z = f2bf(v.z); o.w = f2bf(v.w);
        *(ushort4*)(d + i) = o;
        return;
    }
    // ---- table row r: 1 thread per token, wave+LDS reduce ----
    __shared__ int sl[4], sc[4];
    const bool isb = mask_is_byte(qmask);
    const int r = blockIdx.x - 2048;             // 0..31
    const int t = tid;                           // 0..255 (= T_SZ)
    const int pm = mget(pmask, r * T_SZ + t, isb);
    const int qm = mget(qmask, r * T_SZ + t, isb);
    maddF[r * T_SZ + t] = pm ? 0.0f : -1e30f;
    qmulF[r * T_SZ + t] = qm ? 1.0f : 0.0f;
    int lp = pm ? t + 1 : 0, cq = qm;
    #pragma unroll
    for (int off = 1; off < 64; off <<= 1) {
        int o = __shfl_xor(lp, off);
        lp = o > lp ? o : lp;
        cq += __shfl_xor(cq, off);
    }
    if ((tid & 63) == 0) { sl[tid >> 6] = lp; sc[tid >> 6] = cq; }
    __syncthreads();
    if (tid == 0) {
        int LP = sl[0], CQ = sc[0];
        #pragma unroll
        for (int i = 1; i < 4; ++i) { LP = sl[i] > LP ? sl[i] : LP; CQ += sc[i]; }
        p_hiA[r] = LP > 1 ? LP : 1;
        tcntA[r] = (float)(CQ > 1 ? CQ : 1);
    }
}

// ---------------- Kernel B: late-interaction scores (unchanged R11) ---------
__global__ __launch_bounds__(512, 4) void late_sim(
    const unsigned short* __restrict__ Qbf, const unsigned short* __restrict__ Pbf,
    const float* __restrict__ maddF, const float* __restrict__ qmulF,
    const int* __restrict__ p_hiA, float* __restrict__ sraw)
{
    __shared__ __align__(16) unsigned char Plds[T_SZ * D_SZ * 2]; // 64 KB
    __shared__ float madd[T_SZ];
    __shared__ float qmul[2][T_SZ];
    __shared__ float wsum[2][8];

    const int tid = threadIdx.x;
    const int l   = tid & 63;
    const int w   = tid >> 6;        // wave 0..7
    const int bid = blockIdx.x;
    const int xcd = bid & 7;
    const int idx = bid >> 3;        // 0..63
    const int bg  = xcd * 2 + (idx >> 5);  // XCD-local bg pair
    const int c   = idx & 31;
    const int b0  = bg, b1 = bg + 16;
    const int lr  = l & 15;
    const int lg  = l >> 4;

    const int p_hi    = p_hiA[c];
    const int ptmax   = (p_hi + 15) >> 4;   // 16-row MFMA tiles
    const int stiters = (p_hi + 31) >> 5;   // 32-row staging iterations

    // wave-uniform q-tile activity
    const int qrow = w * 32 + (l & 31);
    const bool do0 = __any(qmulF[b0 * T_SZ + qrow] > 0.0f);
    const bool do1 = __any(qmulF[b1 * T_SZ + qrow] > 0.0f);

    // Q fragments FIRST (in flight while staging runs)
    bf16x8 qf0[2][4] = {}, qf1[2][4] = {};
    if (do0)
        #pragma unroll
        for (int qt = 0; qt < 2; ++qt)
            #pragma unroll
            for (int k = 0; k < 4; ++k)
                qf0[qt][k] = *(const bf16x8*)(Qbf + b0 * (T_SZ * D_SZ)
                              + (w * 32 + qt * 16 + lr) * D_SZ + k * 32 + lg * 8);
    if (do1)
        #pragma unroll
        for (int qt = 0; qt < 2; ++qt)
            #pragma unroll
            for (int k = 0; k < 4; ++k)
                qf1[qt][k] = *(const bf16x8*)(Qbf + b1 * (T_SZ * D_SZ)
                              + (w * 32 + qt * 16 + lr) * D_SZ + k * 32 + lg * 8);

    // stage P rows [0, stiters*32): global_load_lds, linear LDS dest,
    // inverse-swizzled global source (read-side XOR makes it net-identity)
    {
        const unsigned short* Pc = Pbf + c * (T_SZ * D_SZ);
        for (int it = 0; it < stiters; ++it) {
            int j   = it * 512 + w * 64 + l;     // linear 16B chunk id
            int row = j >> 4;
            int cj  = j & 15;
            const unsigned short* src = Pc + row * D_SZ + ((cj ^ (row & 7)) << 3);
            __builtin_amdgcn_global_load_lds(
                (const __attribute__((address_space(1))) unsigned int*)src,
                (__attribute__((address_space(3))) unsigned int*)(Plds + (it * 512 + w * 64) * 16),
                16, 0, 0);
        }
    }
    // mask vectors LDS fill (vectorized from precomputed tables)
    if (tid < 64) {
        *(float4*)(madd + tid * 4) = *(const float4*)(maddF + c * T_SZ + tid * 4);
    } else if (tid < 128) {
        int t = tid - 64;
        *(float4*)(qmul[0] + t * 4) = *(const float4*)(qmulF + b0 * T_SZ + t * 4);
    } else if (tid < 192) {
        int t = tid - 128;
        *(float4*)(qmul[1] + t * 4) = *(const float4*)(qmulF + b1 * T_SZ + t * 4);
    }
    __syncthreads();   // drains vmcnt(0): staging + qf loads complete

    float r00 = -3e38f, r01 = -3e38f, r10 = -3e38f, r11 = -3e38f;

    for (int pt = 0; pt < ptmax; ++pt) {
        f32x4 a00 = {0,0,0,0}, a01 = {0,0,0,0}, a10 = {0,0,0,0}, a11 = {0,0,0,0};
        #pragma unroll
        for (int k = 0; k < 4; ++k) {
            int row = pt * 16 + lr;
            bf16x8 af = *(const bf16x8*)(Plds + row * 256 + (((k * 4 + lg) ^ (row & 7)) << 4));
            if (do0) {
                a00 = __builtin_amdgcn_mfma_f32_16x16x32_bf16(af, qf0[0][k], a00, 0, 0, 0);
                a01 = __builtin_amdgcn_mfma_f32_16x16x32_bf16(af, qf0[1][k], a01, 0, 0, 0);
            }
            if (do1) {
                a10 = __builtin_amdgcn_mfma_f32_16x16x32_bf16(af, qf1[0][k], a10, 0, 0, 0);
                a11 = __builtin_amdgcn_mfma_f32_16x16x32_bf16(af, qf1[1][k], a11, 0, 0, 0);
            }
        }
        // C layout: col(q)=lane&15, row(p)= pt*16 + lg*4 + reg
        float pm0 = madd[pt * 16 + lg * 4 + 0];
        float pm1 = madd[pt * 16 + lg * 4 + 1];
        float pm2 = madd[pt * 16 + lg * 4 + 2];
        float pm3v = madd[pt * 16 + lg * 4 + 3];
        if (do0) {
            r00 = fmaxf(r00, fmaxf(fmaxf(a00[0]+pm0, a00[1]+pm1), fmaxf(a00[2]+pm2, a00[3]+pm3v)));
            r01 = fmaxf(r01, fmaxf(fmaxf(a01[0]+pm0, a01[1]+pm1), fmaxf(a01[2]+pm2, a01[3]+pm3v)));
        }
        if (do1) {
            r10 = fmaxf(r10, fmaxf(fmaxf(a10[0]+pm0, a10[1]+pm1), fmaxf(a10[2]+pm2, a10[3]+pm3v)));
            r11 = fmaxf(r11, fmaxf(fmaxf(a11[0]+pm0, a11[1]+pm1), fmaxf(a11[2]+pm2, a11[3]+pm3v)));
        }
    }

    // combine the 4 row-groups (lanes x, 16+x, 32+x, 48+x)
    r00 = fmaxf(r00, __shfl_xor(r00, 16)); r00 = fmaxf(r00, __shfl_xor(r00, 32));
    r01 = fmaxf(r01, __shfl_xor(r01, 16)); r01 = fmaxf(r01, __shfl_xor(r01, 32));
    r10 = fmaxf(r10, __shfl_xor(r10, 16)); r10 = fmaxf(r10, __shfl_xor(r10, 32));
    r11 = fmaxf(r11, __shfl_xor(r11, 16)); r11 = fmaxf(r11, __shfl_xor(r11, 32));

    // masked sum over this wave's 32 q tokens (each value replicated 4x)
    float t0 = r00 * qmul[0][w * 32 + lr] + r01 * qmul[0][w * 32 + 16 + lr];
    float t1 = r10 * qmul[1][w * 32 + lr] + r11 * qmul[1][w * 32 + 16 + lr];
    #pragma unroll
    for (int off = 32; off > 0; off >>= 1) {
        t0 += __shfl_down(t0, off);
        t1 += __shfl_down(t1, off);
    }
    if (l == 0) { wsum[0][w] = t0 * 0.25f; wsum[1][w] = t1 * 0.25f; }
    __syncthreads();

    if (tid == 0) {
        float s0 = 0.f, s1 = 0.f;
        #pragma unroll
        for (int ww = 0; ww < 8; ++ww) { s0 += wsum[0][ww]; s1 += wsum[1][ww]; }
        sraw[b0 * 32 + c] = s0;
        sraw[b1 * 32 + c] = s1;
    }
}

// ---------------- Kernel C: losses, one block PER ROW (32 blocks) -----------
// Block r: dense row r (8 threads/column x 16 elems each, shuffle-reduce),
// late row r from sraw/tcntA, 32-lane softmax/CE/KL, atomicAdd /32
// contribution into out (zeroed by a hipMemsetAsync node each call).
__global__ __launch_bounds__(256) void loss_row(
    const float* __restrict__ qs, const float* __restrict__ ps,
    const float* __restrict__ sraw, const float* __restrict__ tcntA,
    float* __restrict__ out)
{
    __shared__ float denseL[B_SZ], lateL[B_SZ];
    const int r   = blockIdx.x;
    const int tid = threadIdx.x;
    const int cc  = tid >> 3;        // column 0..31
    const int j   = tid & 7;         // 16-elem chunk within the dot

    // dot(qs[r], ps[cc]): 8 threads x 16 elems (4x float4), 3-round reduce
    {
        const float4* qa = (const float4*)(qs + r  * D_SZ + j * 16);
        const float4* pb = (const float4*)(ps + cc * D_SZ + j * 16);
        float s = 0.f;
        #pragma unroll
        for (int v = 0; v < 4; ++v) {
            float4 q = qa[v], p = pb[v];
            s += q.x * p.x + q.y * p.y + q.z * p.z + q.w * p.w;
        }
        s += __shfl_xor(s, 1);
        s += __shfl_xor(s, 2);
        s += __shfl_xor(s, 4);
        if (j == 0) denseL[cc] = s;
    }
    if (tid < B_SZ) lateL[tid] = sraw[r * 32 + tid] / tcntA[r];
    __syncthreads();

    if (tid >= 32) return;
    const int lane = tid;            // 0..31 within wave 0
    float xd = denseL[lane] * TAU_INV;
    float xl = lateL[lane]  * TAU_INV;
    float md = xd, ml = xl;
    #pragma unroll
    for (int off = 16; off > 0; off >>= 1) {
        md = fmaxf(md, __shfl_xor(md, off));
        ml = fmaxf(ml, __shfl_xor(ml, off));
    }
    float sd = expf(xd - md), sl = expf(xl - ml);
    #pragma unroll
    for (int off = 16; off > 0; off >>= 1) {
        sd += __shfl_xor(sd, off);
        sl += __shfl_xor(sl, off);
    }
    float lsd = md + logf(sd);
    float lsl = ml + logf(sl);
    float pd = expf(xd - lsd);
    float pl = expf(xl - lsl);
    float klt = pd * logf((pd + 1e-8f) / (pl + 1e-8f));
    #pragma unroll
    for (int off = 16; off > 0; off >>= 1) klt += __shfl_xor(klt, off);

    float logpd = xd - lsd;          // lane cc holds col cc of row r
    float logpl = xl - lsl;
    float dlogd = __shfl(logpd, r);  // diagonal entry (lane r)
    float dlogl = __shfl(logpl, r);

    if (lane == 0) {
        const float inv = 1.0f / (float)B_SZ;
        float a = -dlogd * inv;      // single CE contribution
        float b = -dlogl * inv;      // multi CE contribution
        float k = klt * inv;         // KL contribution
        atomicAdd(out + 1, a);
        atomicAdd(out + 2, b);
        atomicAdd(out + 3, k);
        atomicAdd(out + 0, a + b + k);
    }
}

// ---------------------------------------------------------------------------
extern "C" void kernel_launch(void* const* d_in, const int* in_sizes, int n_in,
                              void* d_out, int out_size, void* d_ws, size_t ws_size,
                              hipStream_t stream) {
    const float* qs    = (const float*)d_in[0];  // query_single [32,128]
    const float* ps    = (const float*)d_in[1];  // pos_single   [32,128]
    const float* qm3   = (const float*)d_in[2];  // query_multi  [32,256,128]
    const float* pm3   = (const float*)d_in[3];  // pos_multi    [32,256,128]
    const void*  qmask = d_in[4];                // q_mask [32,256]
    const void*  pmask = d_in[5];                // p_mask [32,256]
    float* out = (float*)d_out;

    const int NTOK = B_SZ * T_SZ * D_SZ;         // 1,048,576
    unsigned short* Qbf = (unsigned short*)d_ws;
    unsigned short* Pbf = Qbf + NTOK;
    float* sraw  = (float*)(Pbf + NTOK);         // [1024]
    float* maddF = sraw + 1024;                  // [32*256]
    float* qmulF = maddF + B_SZ * T_SZ;          // [32*256]
    int*   p_hiA = (int*)(qmulF + B_SZ * T_SZ);  // [32]
    float* tcntA = (float*)(p_hiA + 32);         // [32]

    hipMemsetAsync(out, 0, 4 * sizeof(float), stream);  // atomics accumulate
    cvt_prep<<<2080, 256, 0, stream>>>(qm3, pm3, qmask, pmask, Qbf, Pbf,
                                       maddF, qmulF, p_hiA, tcntA);
    late_sim<<<512, 512, 0, stream>>>(Qbf, Pbf, maddF, qmulF, p_hiA, sraw);
    loss_row<<<B_SZ, 256, 0, stream>>>(qs, ps, sraw, tcntA, out);
}

// Round 14
// 34.234 us; speedup vs baseline: 1.6213x; 1.0438x over previous
//
#include <hip/hip_runtime.h>
#include <hip/hip_bf16.h>

// Problem constants (from reference): B=32, T=256, D=128, tau=0.02
#define B_SZ 32
#define T_SZ 256
#define D_SZ 128
#define TAU_INV 50.0f

typedef __bf16 bf16x8 __attribute__((ext_vector_type(8)));
typedef float f32x4 __attribute__((ext_vector_type(4)));

__device__ __forceinline__ unsigned short f2bf(float f) {
    union { float f; unsigned int u; } v; v.f = f;
    unsigned int r = v.u + 0x7fffu + ((v.u >> 16) & 1u);  // RNE
    return (unsigned short)(r >> 16);
}

// masks arrive either as int32 (harness "integer -> int*") or raw bool bytes.
// Element [0][0] is always true (q_len,p_len >= 64), so int32 layout reads 1,
// byte layout reads 0x01010101. Deterministic (input-only) detection.
__device__ __forceinline__ bool mask_is_byte(const void* m) {
    return ((const int*)m)[0] != 1;
}
__device__ __forceinline__ int mget(const void* m, int idx, bool isb) {
    return isb ? (((const unsigned char*)m)[idx] != 0) : (((const int*)m)[idx] != 0);
}

// ---------------- Kernel A: fp32->bf16 + mask tables ------------------------
// Blocks 0..511: convert (each thread 8 elems of Q AND 8 of P).
// Blocks 512..543: one block per batch row r -> maddF/qmulF, p_hi[r], tcnt[r].
__global__ __launch_bounds__(256) void cvt_prep2(
    const float* __restrict__ qsrc, const float* __restrict__ psrc,
    const void* __restrict__ qmask, const void* __restrict__ pmask,
    unsigned short* __restrict__ Qb, unsigned short* __restrict__ Pb,
    float* __restrict__ maddF, float* __restrict__ qmulF,
    int* __restrict__ p_hiA, float* __restrict__ tcntA) {
    const int tid = threadIdx.x;
    if (blockIdx.x < 512) {
        int i = (blockIdx.x * 256 + tid) * 8;
        const float4* q4 = (const float4*)(qsrc + i);
        const float4* p4 = (const float4*)(psrc + i);
        float4 a0 = q4[0], a1 = q4[1], b0 = p4[0], b1 = p4[1];
        ushort4 oq0 = { f2bf(a0.x), f2bf(a0.y), f2bf(a0.z), f2bf(a0.w) };
        ushort4 oq1 = { f2bf(a1.x), f2bf(a1.y), f2bf(a1.z), f2bf(a1.w) };
        ushort4 op0 = { f2bf(b0.x), f2bf(b0.y), f2bf(b0.z), f2bf(b0.w) };
        ushort4 op1 = { f2bf(b1.x), f2bf(b1.y), f2bf(b1.z), f2bf(b1.w) };
        *(ushort4*)(Qb + i)     = oq0;
        *(ushort4*)(Qb + i + 4) = oq1;
        *(ushort4*)(Pb + i)     = op0;
        *(ushort4*)(Pb + i + 4) = op1;
        return;
    }
    // ---- table row r: 1 thread per token, wave+LDS reduce ----
    __shared__ int sl[4], sc[4];
    const bool isb = mask_is_byte(qmask);
    const int r = blockIdx.x - 512;              // 0..31
    const int t = tid;                           // 0..255 (= T_SZ)
    const int pm = mget(pmask, r * T_SZ + t, isb);
    const int qm = mget(qmask, r * T_SZ + t, isb);
    maddF[r * T_SZ + t] = pm ? 0.0f : -1e30f;
    qmulF[r * T_SZ + t] = qm ? 1.0f : 0.0f;
    int lp = pm ? t + 1 : 0, cq = qm;
    #pragma unroll
    for (int off = 1; off < 64; off <<= 1) {
        int o = __shfl_xor(lp, off);
        lp = o > lp ? o : lp;
        cq += __shfl_xor(cq, off);
    }
    if ((tid & 63) == 0) { sl[tid >> 6] = lp; sc[tid >> 6] = cq; }
    __syncthreads();
    if (tid == 0) {
        int LP = sl[0], CQ = sc[0];
        #pragma unroll
        for (int i = 1; i < 4; ++i) { LP = sl[i] > LP ? sl[i] : LP; CQ += sc[i]; }
        p_hiA[r] = LP > 1 ? LP : 1;
        tcntA[r] = (float)(CQ > 1 ? CQ : 1);
    }
}

// ---------------- Kernel B: late-interaction, 2 c's per block ---------------
// 256 blocks x 1024 threads, 1 block/CU, 16 waves. Block (bg, cp): b0=bg,
// b1=bg+16, c0=2cp, c1=2cp+1. Waves 0-7 own b0 (32 q-rows each), 8-15 own b1.
// P tiles double-buffered in 128 KB LDS: stage c0 -> barrier -> issue c1
// stage -> compute c0 (c1 latency hidden) -> barrier -> compute c1.
// global_load_lds with linear LDS dest + inverse-swizzled global source;
// swizzled reads make it net-identity (rule #21).
__global__ __launch_bounds__(1024, 4) void late_sim2(
    const unsigned short* __restrict__ Qbf, const unsigned short* __restrict__ Pbf,
    const float* __restrict__ maddF, const float* __restrict__ qmulF,
    const int* __restrict__ p_hiA, float* __restrict__ sraw)
{
    __shared__ __align__(16) unsigned char Pl[2][T_SZ * D_SZ * 2]; // 2 x 64 KB
    __shared__ float maddL[2][T_SZ];
    __shared__ float qmulL[2][T_SZ];
    __shared__ float wsum[16][2];

    const int tid = threadIdx.x;
    const int l   = tid & 63;
    const int w   = tid >> 6;            // wave 0..15
    const int bid = blockIdx.x;
    const int xcd = bid & 7;
    const int j   = bid >> 3;            // 0..31
    const int bg  = xcd * 2 + (j >> 4);  // XCD-local bg
    const int cp  = j & 15;
    const int c0  = cp * 2, c1 = cp * 2 + 1;
    const int b0  = bg, b1 = bg + 16;
    const int lr  = l & 15;
    const int lg  = l >> 4;
    const int wb  = w >> 3;              // 0: b0 waves, 1: b1 waves
    const int myb = wb ? b1 : b0;
    const int s   = (w & 7) * 32;        // this wave's q-row strip

    const int p_hi0 = p_hiA[c0], p_hi1 = p_hiA[c1];
    const int pt0 = (p_hi0 + 15) >> 4, st0 = (p_hi0 + 63) >> 6;
    const int pt1 = (p_hi1 + 15) >> 4, st1 = (p_hi1 + 63) >> 6;

    // wave-uniform q activity for this wave's 32 rows
    const bool dob = __any(qmulF[myb * T_SZ + s + (l & 31)] > 0.0f);

    // Q fragments (one b per wave): lane holds Q[s+qt*16+lr][k*32+lg*8..]
    bf16x8 qf[2][4] = {};
    if (dob)
        #pragma unroll
        for (int qt = 0; qt < 2; ++qt)
            #pragma unroll
            for (int k = 0; k < 4; ++k)
                qf[qt][k] = *(const bf16x8*)(Qbf + myb * (T_SZ * D_SZ)
                              + (s + qt * 16 + lr) * D_SZ + k * 32 + lg * 8);

    // stage c0 (buffer 0): 1024 thr x 16B = 64 rows per iteration
    {
        const unsigned short* Pc = Pbf + c0 * (T_SZ * D_SZ);
        for (int it = 0; it < st0; ++it) {
            int m   = it * 1024 + tid;           // linear 16B chunk id
            int row = m >> 4;
            int cj  = m & 15;
            const unsigned short* src = Pc + row * D_SZ + ((cj ^ (row & 7)) << 3);
            __builtin_amdgcn_global_load_lds(
                (const __attribute__((address_space(1))) unsigned int*)src,
                (__attribute__((address_space(3))) unsigned int*)(Pl[0] + (it * 1024 + w * 64) * 16),
                16, 0, 0);
        }
    }
    // mask vectors (from precomputed tables)
    if (tid < 64) {
        *(float4*)(maddL[0] + tid * 4) = *(const float4*)(maddF + c0 * T_SZ + tid * 4);
    } else if (tid < 128) {
        int t = tid - 64;
        *(float4*)(maddL[1] + t * 4) = *(const float4*)(maddF + c1 * T_SZ + t * 4);
    } else if (tid < 192) {
        int t = tid - 128;
        *(float4*)(qmulL[0] + t * 4) = *(const float4*)(qmulF + b0 * T_SZ + t * 4);
    } else if (tid < 256) {
        int t = tid - 192;
        *(float4*)(qmulL[1] + t * 4) = *(const float4*)(qmulF + b1 * T_SZ + t * 4);
    }
    __syncthreads();                             // c0 + masks ready

    // issue c1 staging (buffer 1) — hides under c0 compute
    {
        const unsigned short* Pc = Pbf + c1 * (T_SZ * D_SZ);
        for (int it = 0; it < st1; ++it) {
            int m   = it * 1024 + tid;
            int row = m >> 4;
            int cj  = m & 15;
            const unsigned short* src = Pc + row * D_SZ + ((cj ^ (row & 7)) << 3);
            __builtin_amdgcn_global_load_lds(
                (const __attribute__((address_space(1))) unsigned int*)src,
                (__attribute__((address_space(3))) unsigned int*)(Pl[1] + (it * 1024 + w * 64) * 16),
                16, 0, 0);
        }
    }

    float r00 = -3e38f, r01 = -3e38f;            // c0: qt0, qt1
    float r10 = -3e38f, r11 = -3e38f;            // c1: qt0, qt1

    for (int pt = 0; pt < pt0; ++pt) {           // ---- compute c0 ----
        f32x4 a0 = {0,0,0,0}, a1 = {0,0,0,0};
        #pragma unroll
        for (int k = 0; k < 4; ++k) {
            int row = pt * 16 + lr;
            bf16x8 af = *(const bf16x8*)(Pl[0] + row * 256 + (((k * 4 + lg) ^ (row & 7)) << 4));
            if (dob) {
                a0 = __builtin_amdgcn_mfma_f32_16x16x32_bf16(af, qf[0][k], a0, 0, 0, 0);
                a1 = __builtin_amdgcn_mfma_f32_16x16x32_bf16(af, qf[1][k], a1, 0, 0, 0);
            }
        }
        float pm0 = maddL[0][pt * 16 + lg * 4 + 0];
        float pm1 = maddL[0][pt * 16 + lg * 4 + 1];
        float pm2 = maddL[0][pt * 16 + lg * 4 + 2];
        float pm3 = maddL[0][pt * 16 + lg * 4 + 3];
        if (dob) {
            r00 = fmaxf(r00, fmaxf(fmaxf(a0[0]+pm0, a0[1]+pm1), fmaxf(a0[2]+pm2, a0[3]+pm3)));
            r01 = fmaxf(r01, fmaxf(fmaxf(a1[0]+pm0, a1[1]+pm1), fmaxf(a1[2]+pm2, a1[3]+pm3)));
        }
    }
    __syncthreads();                             // c1 staged (vmcnt drained)

    for (int pt = 0; pt < pt1; ++pt) {           // ---- compute c1 ----
        f32x4 a0 = {0,0,0,0}, a1 = {0,0,0,0};
        #pragma unroll
        for (int k = 0; k < 4; ++k) {
            int row = pt * 16 + lr;
            bf16x8 af = *(const bf16x8*)(Pl[1] + row * 256 + (((k * 4 + lg) ^ (row & 7)) << 4));
            if (dob) {
                a0 = __builtin_amdgcn_mfma_f32_16x16x32_bf16(af, qf[0][k], a0, 0, 0, 0);
                a1 = __builtin_amdgcn_mfma_f32_16x16x32_bf16(af, qf[1][k], a1, 0, 0, 0);
            }
        }
        float pm0 = maddL[1][pt * 16 + lg * 4 + 0];
        float pm1 = maddL[1][pt * 16 + lg * 4 + 1];
        float pm2 = maddL[1][pt * 16 + lg * 4 + 2];
        float pm3 = maddL[1][pt * 16 + lg * 4 + 3];
        if (dob) {
            r10 = fmaxf(r10, fmaxf(fmaxf(a0[0]+pm0, a0[1]+pm1), fmaxf(a0[2]+pm2, a0[3]+pm3)));
            r11 = fmaxf(r11, fmaxf(fmaxf(a1[0]+pm0, a1[1]+pm1), fmaxf(a1[2]+pm2, a1[3]+pm3)));
        }
    }

    // combine the 4 row-groups (lanes x, 16+x, 32+x, 48+x)
    r00 = fmaxf(r00, __shfl_xor(r00, 16)); r00 = fmaxf(r00, __shfl_xor(r00, 32));
    r01 = fmaxf(r01, __shfl_xor(r01, 16)); r01 = fmaxf(r01, __shfl_xor(r01, 32));
    r10 = fmaxf(r10, __shfl_xor(r10, 16)); r10 = fmaxf(r10, __shfl_xor(r10, 32));
    r11 = fmaxf(r11, __shfl_xor(r11, 16)); r11 = fmaxf(r11, __shfl_xor(r11, 32));

    // masked sum over this wave's 32 q tokens (each value replicated 4x)
    float t0 = r00 * qmulL[wb][s + lr] + r01 * qmulL[wb][s + 16 + lr];   // c0
    float t1 = r10 * qmulL[wb][s + lr] + r11 * qmulL[wb][s + 16 + lr];   // c1
    #pragma unroll
    for (int off = 32; off > 0; off >>= 1) {
        t0 += __shfl_down(t0, off);
        t1 += __shfl_down(t1, off);
    }
    if (l == 0) { wsum[w][0] = t0 * 0.25f; wsum[w][1] = t1 * 0.25f; }
    __syncthreads();

    if (tid < 4) {                               // tid: bit0=c, bit1=b
        const int bsel = tid >> 1, csel = tid & 1;
        float sum = 0.f;
        #pragma unroll
        for (int ww = 0; ww < 8; ++ww) sum += wsum[bsel * 8 + ww][csel];
        sraw[(bsel ? b1 : b0) * 32 + (csel ? c1 : c0)] = sum;
    }
}

// ---------------- Kernel C: losses, one block PER ROW (32 blocks) -----------
__global__ __launch_bounds__(256) void loss_row(
    const float* __restrict__ qs, const float* __restrict__ ps,
    const float* __restrict__ sraw, const float* __restrict__ tcntA,
    float* __restrict__ out)
{
    __shared__ float denseL[B_SZ], lateL[B_SZ];
    const int r   = blockIdx.x;
    const int tid = threadIdx.x;
    const int cc  = tid >> 3;        // column 0..31
    const int j   = tid & 7;         // 16-elem chunk within the dot

    // dot(qs[r], ps[cc]): 8 threads x 16 elems (4x float4), 3-round reduce
    {
        const float4* qa = (const float4*)(qs + r  * D_SZ + j * 16);
        const float4* pb = (const float4*)(ps + cc * D_SZ + j * 16);
        float s = 0.f;
        #pragma unroll
        for (int v = 0; v < 4; ++v) {
            float4 q = qa[v], p = pb[v];
            s += q.x * p.x + q.y * p.y + q.z * p.z + q.w * p.w;
        }
        s += __shfl_xor(s, 1);
        s += __shfl_xor(s, 2);
        s += __shfl_xor(s, 4);
        if (j == 0) denseL[cc] = s;
    }
    if (tid < B_SZ) lateL[tid] = sraw[r * 32 + tid] / tcntA[r];
    __syncthreads();

    if (tid >= 32) return;
    const int lane = tid;
    float xd = denseL[lane] * TAU_INV;
    float xl = lateL[lane]  * TAU_INV;
    float md = xd, ml = xl;
    #pragma unroll
    for (int off = 16; off > 0; off >>= 1) {
        md = fmaxf(md, __shfl_xor(md, off));
        ml = fmaxf(ml, __shfl_xor(ml, off));
    }
    float sd = expf(xd - md), sl = expf(xl - ml);
    #pragma unroll
    for (int off = 16; off > 0; off >>= 1) {
        sd += __shfl_xor(sd, off);
        sl += __shfl_xor(sl, off);
    }
    float lsd = md + logf(sd);
    float lsl = ml + logf(sl);
    float pd = expf(xd - lsd);
    float pl = expf(xl - lsl);
    float klt = pd * logf((pd + 1e-8f) / (pl + 1e-8f));
    #pragma unroll
    for (int off = 16; off > 0; off >>= 1) klt += __shfl_xor(klt, off);

    float logpd = xd - lsd;
    float logpl = xl - lsl;
    float dlogd = __shfl(logpd, r);
    float dlogl = __shfl(logpl, r);

    if (lane == 0) {
        const float inv = 1.0f / (float)B_SZ;
        float a = -dlogd * inv;
        float b = -dlogl * inv;
        float k = klt * inv;
        atomicAdd(out + 1, a);
        atomicAdd(out + 2, b);
        atomicAdd(out + 3, k);
        atomicAdd(out + 0, a + b + k);
    }
}

// ---------------------------------------------------------------------------
extern "C" void kernel_launch(void* const* d_in, const int* in_sizes, int n_in,
                              void* d_out, int out_size, void* d_ws, size_t ws_size,
                              hipStream_t stream) {
    const float* qs    = (const float*)d_in[0];  // query_single [32,128]
    const float* ps    = (const float*)d_in[1];  // pos_single   [32,128]
    const float* qm3   = (const float*)d_in[2];  // query_multi  [32,256,128]
    const float* pm3   = (const float*)d_in[3];  // pos_multi    [32,256,128]
    const void*  qmask = d_in[4];                // q_mask [32,256]
    const void*  pmask = d_in[5];                // p_mask [32,256]
    float* out = (float*)d_out;

    const int NTOK = B_SZ * T_SZ * D_SZ;         // 1,048,576
    unsigned short* Qbf = (unsigned short*)d_ws;
    unsigned short* Pbf = Qbf + NTOK;
    float* sraw  = (float*)(Pbf + NTOK);         // [1024]
    float* maddF = sraw + 1024;                  // [32*256]
    float* qmulF = maddF + B_SZ * T_SZ;          // [32*256]
    int*   p_hiA = (int*)(qmulF + B_SZ * T_SZ);  // [32]
    float* tcntA = (float*)(p_hiA + 32);         // [32]

    hipMemsetAsync(out, 0, 4 * sizeof(float), stream);  // atomics accumulate
    cvt_prep2<<<544, 256, 0, stream>>>(qm3, pm3, qmask, pmask, Qbf, Pbf,
                                       maddF, qmulF, p_hiA, tcntA);
    late_sim2<<<256, 1024, 0, stream>>>(Qbf, Pbf, maddF, qmulF, p_hiA, sraw);
    loss_row<<<B_SZ, 256, 0, stream>>>(qs, ps, sraw, tcntA, out);
}